// Round 3
// baseline (377.500 us; speedup 1.0000x reference)
//
#include <hip/hip_runtime.h>

// ---------------------------------------------------------------------------
// GNN: 3x GraphConv(H=64) + global_mean_pool + Linear(64->2)
// N=100000, E=1200000, G=256, C_IN=1, C_OUT=2
//
// Round-3: k_node2 -> thread-per-node register GEMM with wave-uniform
// (scalar-cache) weight reads. No LDS, no staging, no bank conflicts.
// ---------------------------------------------------------------------------

static __device__ __forceinline__ float4 ld4(const float* p) {
    return *reinterpret_cast<const float4*>(p);
}

// Precompute:
//  Wc[j][0..127]  = { W2_rel[k][j] k=0..63 , W2_root[k][j] k=0..63 }  (32 KB)
//  MC4[j]         = { Mrel[j][0], Mrel[j][1], Mroot[j][0], Mroot[j][1] }
//  b3W[c]         = b3 @ W_lin
__global__ void k_small(const float* __restrict__ W3_rel, const float* __restrict__ b3,
                        const float* __restrict__ W3_root, const float* __restrict__ W_lin,
                        const float* __restrict__ W2_rel, const float* __restrict__ W2_root,
                        float4* __restrict__ MC4, float* __restrict__ b3W,
                        float* __restrict__ Wc)
{
    int t = threadIdx.x;
    for (int i = t; i < 8192; i += 256) {
        int j = i >> 7, r = i & 127;
        Wc[i] = (r < 64) ? W2_rel[r * 64 + j] : W2_root[(r - 64) * 64 + j];
    }
    if (t < 64) {
        float sr0 = 0.f, sr1 = 0.f, so0 = 0.f, so1 = 0.f;
        for (int k = 0; k < 64; ++k) {
            float wl0 = W_lin[k * 2 + 0], wl1 = W_lin[k * 2 + 1];
            sr0 += W3_rel[t * 64 + k] * wl0;
            sr1 += W3_rel[t * 64 + k] * wl1;
            so0 += W3_root[t * 64 + k] * wl0;
            so1 += W3_root[t * 64 + k] * wl1;
        }
        MC4[t] = make_float4(sr0, sr1, so0, so1);
    }
    if (t < 2) {
        float s = 0.f;
        for (int k = 0; k < 64; ++k) s += b3[k] * W_lin[k * 2 + t];
        b3W[t] = s;
    }
}

// ---- CSR build -------------------------------------------------------------
__global__ __launch_bounds__(256) void k_hist(const int* __restrict__ dst,
                                              int* __restrict__ deg, int E)
{
    int e = blockIdx.x * 256 + threadIdx.x;
    if (e < E) atomicAdd(&deg[dst[e]], 1);
}

__global__ __launch_bounds__(256) void k_blocksum(const int* __restrict__ deg,
                                                  int* __restrict__ bsum, int N)
{
    __shared__ int s[256];
    int i = blockIdx.x * 256 + threadIdx.x;
    s[threadIdx.x] = (i < N) ? deg[i] : 0;
    __syncthreads();
    for (int o = 128; o > 0; o >>= 1) {
        if (threadIdx.x < o) s[threadIdx.x] += s[threadIdx.x + o];
        __syncthreads();
    }
    if (threadIdx.x == 0) bsum[blockIdx.x] = s[0];
}

__global__ __launch_bounds__(256) void k_scanbsum(const int* __restrict__ bsum,
                                                  int* __restrict__ bpref, int nb)
{
    __shared__ int s[256];
    __shared__ int carry;
    if (threadIdx.x == 0) carry = 0;
    __syncthreads();
    for (int base = 0; base < nb; base += 256) {
        int i = base + threadIdx.x;
        int v = (i < nb) ? bsum[i] : 0;
        s[threadIdx.x] = v;
        __syncthreads();
        for (int off = 1; off < 256; off <<= 1) {
            int t = (threadIdx.x >= off) ? s[threadIdx.x - off] : 0;
            __syncthreads();
            s[threadIdx.x] += t;
            __syncthreads();
        }
        if (i < nb) bpref[i] = carry + s[threadIdx.x] - v;  // exclusive
        __syncthreads();
        if (threadIdx.x == 0) carry += s[255];
        __syncthreads();
    }
}

__global__ __launch_bounds__(256) void k_scan3(const int* __restrict__ deg,
                                               const int* __restrict__ bpref,
                                               int* __restrict__ rowptr, int N, int E)
{
    __shared__ int s[256];
    int i = blockIdx.x * 256 + threadIdx.x;
    int v = (i < N) ? deg[i] : 0;
    s[threadIdx.x] = v;
    __syncthreads();
    for (int off = 1; off < 256; off <<= 1) {
        int t = (threadIdx.x >= off) ? s[threadIdx.x - off] : 0;
        __syncthreads();
        s[threadIdx.x] += t;
        __syncthreads();
    }
    if (i < N) rowptr[i] = bpref[blockIdx.x] + s[threadIdx.x] - v;
    if (blockIdx.x == 0 && threadIdx.x == 0) rowptr[N] = E;
}

__global__ __launch_bounds__(256) void k_scatter(const int* __restrict__ src,
                                                 const int* __restrict__ dst,
                                                 const float* __restrict__ ew,
                                                 const int* __restrict__ rowptr,
                                                 int* __restrict__ cursor,
                                                 int2* __restrict__ csr, int E)
{
    int e = blockIdx.x * 256 + threadIdx.x;
    if (e < E) {
        int d = dst[e];
        int pos = rowptr[d] + atomicAdd(&cursor[d], 1);
        int2 v;
        v.x = src[e];
        v.y = __float_as_int(ew[e]);
        csr[pos] = v;
    }
}

// ---- layer 1: agg1[n] = sum ew*x[src]; pack axn = {agg1, x} ---------------
__global__ __launch_bounds__(256) void k_agg1(const int2* __restrict__ csr,
                                              const int* __restrict__ rowptr,
                                              const float* __restrict__ x,
                                              float2* __restrict__ axn, int N)
{
    int n = blockIdx.x * 256 + threadIdx.x;
    if (n >= N) return;
    int b = rowptr[n], en = rowptr[n + 1];
    float a = 0.f;
    for (int e = b; e < en; ++e) {
        int2 sw = csr[e];
        a = fmaf(__int_as_float(sw.y), x[sw.x], a);
    }
    axn[n] = make_float2(a, x[n]);
}

// ---- layer 2 aggregation: wave per node, lane = channel --------------------
__global__ __launch_bounds__(256) void k_agg2(const int2* __restrict__ csr,
                                              const int* __restrict__ rowptr,
                                              const float2* __restrict__ axn,
                                              const float* __restrict__ W1_rel,
                                              const float* __restrict__ b1,
                                              const float* __restrict__ W1_root,
                                              float* __restrict__ agg2, int N)
{
    int n = (blockIdx.x * 256 + threadIdx.x) >> 6;
    int lane = threadIdx.x & 63;
    if (n >= N) return;
    float wrel = W1_rel[lane], wroot = W1_root[lane], bj = b1[lane];
    int b = rowptr[n], en = rowptr[n + 1];
    float acc = 0.f;
    for (int e = b; e < en; ++e) {
        int2 sw = csr[e];
        float w = __int_as_float(sw.y);
        float2 ax = axn[sw.x];
        float h = fmaxf(fmaf(ax.x, wrel, fmaf(ax.y, wroot, bj)), 0.f);
        acc = fmaf(w, h, acc);
    }
    agg2[(size_t)n * 64 + lane] = acc;
}

// ---- layer-2 node GEMM + layer-3 fold: thread-per-node, scalar weights -----
// h2[j] = relu( sum_k a[k]*Wc[j][k] + h[k]*Wc[j][64+k] + b2[j] )
// z[n]  = { h2 @ Mrel , h2 @ Mroot }  (4 floats)
__global__ __launch_bounds__(256) void k_node2(const float* __restrict__ agg2,
                                               const float2* __restrict__ axn,
                                               const float4* __restrict__ Wc4,   // [64][32]
                                               const float* __restrict__ b2,
                                               const float* __restrict__ W1_rel,
                                               const float* __restrict__ b1,
                                               const float* __restrict__ W1_root,
                                               const float4* __restrict__ MC4,
                                               float4* __restrict__ z, int N)
{
    int n = blockIdx.x * 256 + threadIdx.x;
    if (n >= N) return;

    float4 a[16], h[16];
    const float4* ag = reinterpret_cast<const float4*>(agg2 + (size_t)n * 64);
    float2 ax = axn[n];
#pragma unroll
    for (int q = 0; q < 16; ++q) a[q] = ag[q];
#pragma unroll
    for (int q = 0; q < 16; ++q) {
        float4 wr = ld4(&W1_rel[q * 4]);   // uniform -> scalar cache
        float4 wo = ld4(&W1_root[q * 4]);
        float4 bb = ld4(&b1[q * 4]);
        h[q].x = fmaxf(fmaf(ax.x, wr.x, fmaf(ax.y, wo.x, bb.x)), 0.f);
        h[q].y = fmaxf(fmaf(ax.x, wr.y, fmaf(ax.y, wo.y, bb.y)), 0.f);
        h[q].z = fmaxf(fmaf(ax.x, wr.z, fmaf(ax.y, wo.z, bb.z)), 0.f);
        h[q].w = fmaxf(fmaf(ax.x, wr.w, fmaf(ax.y, wo.w, bb.w)), 0.f);
    }

    float4 zacc = make_float4(0.f, 0.f, 0.f, 0.f);
#pragma unroll 2
    for (int j = 0; j < 64; ++j) {
        const float4* wrow = Wc4 + j * 32;   // uniform across wave -> s_load
        float s0 = 0.f, s1 = 0.f, s2 = 0.f, s3 = 0.f;
#pragma unroll
        for (int q = 0; q < 16; q += 2) {
            float4 w0 = wrow[q],      w1 = wrow[q + 1];
            float4 w2 = wrow[16 + q], w3 = wrow[17 + q];
            s0 = fmaf(a[q].x, w0.x, fmaf(a[q].y, w0.y, fmaf(a[q].z, w0.z, fmaf(a[q].w, w0.w, s0))));
            s1 = fmaf(a[q + 1].x, w1.x, fmaf(a[q + 1].y, w1.y, fmaf(a[q + 1].z, w1.z, fmaf(a[q + 1].w, w1.w, s1))));
            s2 = fmaf(h[q].x, w2.x, fmaf(h[q].y, w2.y, fmaf(h[q].z, w2.z, fmaf(h[q].w, w2.w, s2))));
            s3 = fmaf(h[q + 1].x, w3.x, fmaf(h[q + 1].y, w3.y, fmaf(h[q + 1].z, w3.z, fmaf(h[q + 1].w, w3.w, s3))));
        }
        float h2 = fmaxf((s0 + s1) + (s2 + s3) + b2[j], 0.f);
        float4 m = MC4[j];                   // uniform -> s_load
        zacc.x = fmaf(h2, m.x, zacc.x);
        zacc.y = fmaf(h2, m.y, zacc.y);
        zacc.z = fmaf(h2, m.z, zacc.z);
        zacc.w = fmaf(h2, m.w, zacc.w);
    }
    z[n] = zacc;
}

// ---- pool: per-node CSR gather of edge term + node term, LDS-binned --------
__global__ __launch_bounds__(256) void k_pool(const int2* __restrict__ csr,
                                              const int* __restrict__ rowptr,
                                              const int* __restrict__ batch,
                                              const float* __restrict__ z4,
                                              float* __restrict__ gacc, int N, int G)
{
    extern __shared__ float lds[];  // [G][5]
    for (int i = threadIdx.x; i < 5 * G; i += 256) lds[i] = 0.f;
    __syncthreads();

    int gt = blockIdx.x * 256 + threadIdx.x;
    int TT = gridDim.x * 256;
    for (int n = gt; n < N; n += TT) {
        int bg = batch[n];
        int b = rowptr[n], en = rowptr[n + 1];
        float s0 = 0.f, s1 = 0.f;
        for (int e = b; e < en; ++e) {
            int2 sw = csr[e];
            float w = __int_as_float(sw.y);
            float2 zz = *reinterpret_cast<const float2*>(&z4[(size_t)sw.x * 4]);
            s0 = fmaf(w, zz.x, s0);
            s1 = fmaf(w, zz.y, s1);
        }
        float2 zw = *reinterpret_cast<const float2*>(&z4[(size_t)n * 4 + 2]);
        atomicAdd(&lds[bg * 5 + 0], s0);
        atomicAdd(&lds[bg * 5 + 1], s1);
        atomicAdd(&lds[bg * 5 + 2], zw.x);
        atomicAdd(&lds[bg * 5 + 3], zw.y);
        atomicAdd(&lds[bg * 5 + 4], 1.0f);
    }
    __syncthreads();
    for (int i = threadIdx.x; i < 5 * G; i += 256) {
        float v = lds[i];
        if (v != 0.f) atomicAdd(&gacc[i], v);
    }
}

__global__ void k_final(const float* __restrict__ gacc, const float* __restrict__ b3W,
                        const float* __restrict__ b_lin, float* __restrict__ out, int G)
{
    int t = blockIdx.x * blockDim.x + threadIdx.x;
    if (t < G * 2) {
        int g = t >> 1, c = t & 1;
        float cnt = gacc[g * 5 + 4];
        float s = gacc[g * 5 + c] + gacc[g * 5 + 2 + c] + cnt * b3W[c];
        out[t] = s / fmaxf(cnt, 1.f) + b_lin[c];
    }
}

extern "C" void kernel_launch(void* const* d_in, const int* in_sizes, int n_in,
                              void* d_out, int out_size, void* d_ws, size_t ws_size,
                              hipStream_t stream)
{
    const float* x       = (const float*)d_in[0];
    const int*   ei      = (const int*)  d_in[1];
    const int*   batch   = (const int*)  d_in[2];
    const float* ew      = (const float*)d_in[3];
    const float* W1_rel  = (const float*)d_in[4];
    const float* b1      = (const float*)d_in[5];
    const float* W1_root = (const float*)d_in[6];
    const float* W2_rel  = (const float*)d_in[7];
    const float* b2      = (const float*)d_in[8];
    const float* W2_root = (const float*)d_in[9];
    const float* W3_rel  = (const float*)d_in[10];
    const float* b3      = (const float*)d_in[11];
    const float* W3_root = (const float*)d_in[12];
    const float* W_lin   = (const float*)d_in[13];
    const float* b_lin   = (const float*)d_in[14];
    float* out = (float*)d_out;

    const int N = in_sizes[0];
    const int E = in_sizes[3];
    const int G = out_size / 2;
    const int NB = (N + 255) / 256;
    const int* src = ei;
    const int* dst = ei + E;

    char* wsb = (char*)d_ws;
    size_t o = 0;
    auto take = [&](size_t bytes) -> char* {
        char* p = wsb + o;
        o += (bytes + 15) & ~(size_t)15;
        return p;
    };
    int*    deg    = (int*)   take((size_t)N * 4);
    int*    cursor = (int*)   take((size_t)N * 4);
    float*  gacc   = (float*) take((size_t)G * 5 * 4);
    size_t  zero_bytes = o;
    int*    rowptr = (int*)   take((size_t)(N + 1) * 4);
    int*    bsum   = (int*)   take((size_t)NB * 4);
    int*    bpref  = (int*)   take((size_t)NB * 4);
    int2*   csr    = (int2*)  take((size_t)E * 8);
    float2* axn    = (float2*)take((size_t)N * 8);
    float*  agg2   = (float*) take((size_t)N * 64 * 4);
    float4* z      = (float4*)take((size_t)N * 16);
    float4* MC4    = (float4*)take(64 * 16);
    float*  b3W    = (float*) take(4 * 4);
    float*  Wc     = (float*) take(8192 * 4);

    hipMemsetAsync(d_ws, 0, zero_bytes, stream);

    hipLaunchKernelGGL(k_small, dim3(1), dim3(256), 0, stream,
                       W3_rel, b3, W3_root, W_lin, W2_rel, W2_root,
                       MC4, b3W, Wc);

    hipLaunchKernelGGL(k_hist, dim3((E + 255) / 256), dim3(256), 0, stream, dst, deg, E);
    hipLaunchKernelGGL(k_blocksum, dim3(NB), dim3(256), 0, stream, deg, bsum, N);
    hipLaunchKernelGGL(k_scanbsum, dim3(1), dim3(256), 0, stream, bsum, bpref, NB);
    hipLaunchKernelGGL(k_scan3, dim3(NB), dim3(256), 0, stream, deg, bpref, rowptr, N, E);
    hipLaunchKernelGGL(k_scatter, dim3((E + 255) / 256), dim3(256), 0, stream,
                       src, dst, ew, rowptr, cursor, csr, E);

    hipLaunchKernelGGL(k_agg1, dim3(NB), dim3(256), 0, stream, csr, rowptr, x, axn, N);

    hipLaunchKernelGGL(k_agg2, dim3((N * 64 + 255) / 256), dim3(256), 0, stream,
                       csr, rowptr, axn, W1_rel, b1, W1_root, agg2, N);

    hipLaunchKernelGGL(k_node2, dim3(NB), dim3(256), 0, stream,
                       agg2, axn, (const float4*)Wc, b2, W1_rel, b1, W1_root,
                       MC4, z, N);

    hipLaunchKernelGGL(k_pool, dim3(512), dim3(256), 5 * G * sizeof(float), stream,
                       csr, rowptr, batch, (const float*)z, gacc, N, G);

    hipLaunchKernelGGL(k_final, dim3((G * 2 + 255) / 256), dim3(256), 0, stream,
                       gacc, b3W, b_lin, out, G);
}